// Round 7
// baseline (167.417 us; speedup 1.0000x reference)
//
#include <hip/hip_runtime.h>
#include <hip/hip_bf16.h>

#define B_   16
#define N_   1024
#define INF_ 256
#define NH_  4
#define HD_  256
#define L2E  1.4426950408889634f

typedef __attribute__((ext_vector_type(8))) short short8;
typedef __attribute__((ext_vector_type(4))) float f32x4;

__device__ __forceinline__ float bf2f(unsigned short u) {
    union { unsigned int i; float f; } v; v.i = ((unsigned int)u) << 16; return v.f;
}
__device__ __forceinline__ unsigned short f2bf(float f) {
    union { float f; unsigned int i; } v; v.f = f;
    unsigned int x = v.i;
    return (unsigned short)((x + 0x7fffu + ((x >> 16) & 1u)) >> 16);
}
// pack 2 f32 -> 2 bf16 in one op (low16 = lo, high16 = hi); no builtin on gfx950
__device__ __forceinline__ unsigned int cvt_pk_bf16(float lo, float hi) {
    unsigned int r;
    asm("v_cvt_pk_bf16_f32 %0, %1, %2" : "=v"(r) : "v"(lo), "v"(hi));
    return r;
}
// async global->LDS copy, 16B per lane; LDS dest is wave-uniform base + lane*16
__device__ __forceinline__ void glds16(const void* g, void* l) {
    __builtin_amdgcn_global_load_lds(
        (const __attribute__((address_space(1))) unsigned int*)g,
        (__attribute__((address_space(3))) unsigned int*)l, 16, 0, 0);
}

// ---------------------------------------------------------------------------
// Kernel PREP (fused):
//  blocks [0,2048): pack adj -> row-major bitmask pb[row][word] (uint32,
//    bit p of word w = adj[row][w*32+p]; adj values are exactly 0/1).
//  blocks [2048,2080): W fp32 -> wswz bf16 in MFMA B-frag order.
// ---------------------------------------------------------------------------
__global__ __launch_bounds__(256) void k_prep(const int* __restrict__ adj,
                                              const float* __restrict__ W,
                                              unsigned int* __restrict__ pb,
                                              unsigned short* __restrict__ wswz)
{
    int bx = blockIdx.x, t = threadIdx.x;
    if (bx < 2048) {
        int wave = t >> 6, lane = t & 63;
        int row = bx * 8 + wave * 2 + (lane >> 5);   // [0, 16384)
        int w   = lane & 31;
        const int4* ar = (const int4*)(adj + ((long)row << 10) + w * 32);
        unsigned int u = 0;
        #pragma unroll
        for (int k = 0; k < 8; k++) {
            int4 a = ar[k];
            u |= ((unsigned)a.x) << (4 * k);
            u |= ((unsigned)a.y) << (4 * k + 1);
            u |= ((unsigned)a.z) << (4 * k + 2);
            u |= ((unsigned)a.w) << (4 * k + 3);
        }
        pb[((long)row << 5) + w] = u;
    } else {
        int slot = (bx - 2048) * 256 + t;
        int kstep = slot >> 10;
        int nt    = (slot >> 6) & 15;
        int lane  = slot & 63;
        int k0 = kstep * 32 + (lane >> 4) * 8;
        int n  = nt * 16 + (lane & 15);
        ushort4 o0, o1;
        o0.x = f2bf(W[(k0 + 0) * HD_ + n]);
        o0.y = f2bf(W[(k0 + 1) * HD_ + n]);
        o0.z = f2bf(W[(k0 + 2) * HD_ + n]);
        o0.w = f2bf(W[(k0 + 3) * HD_ + n]);
        o1.x = f2bf(W[(k0 + 4) * HD_ + n]);
        o1.y = f2bf(W[(k0 + 5) * HD_ + n]);
        o1.z = f2bf(W[(k0 + 6) * HD_ + n]);
        o1.w = f2bf(W[(k0 + 7) * HD_ + n]);
        *(ushort4*)&wswz[(long)slot * 8]     = o0;
        *(ushort4*)&wswz[(long)slot * 8 + 4] = o1;
    }
}

// ---------------------------------------------------------------------------
// Kernel A: h = x @ W via MFMA, W-frags from L2 in-loop.
// Block = 256 thr = 4 waves (one head each), 16 rows. grid = 1024.
// Emits hswz (B-frag order bf16) + per-row factors:
//   esr[(b,h,i)]  = exp2(-0.8*ss)   (E1 cancels in softmax -> dropped)
//   edst[(b,h,j)] = {exp2(sd), exp2(0.2*sd)}
// Attention weight (unnormalized) = max(D1_j, r_i*D2_j).
// ---------------------------------------------------------------------------
__global__ __launch_bounds__(256) void k_gemm_h(
    const float* __restrict__ x, const float* __restrict__ a,
    const unsigned short* __restrict__ wswz,
    unsigned short* __restrict__ hswz,
    float* __restrict__ esr, float2* __restrict__ edst)
{
    __shared__ unsigned short xls[16][264];
    int t = threadIdx.x;
    int blk = blockIdx.x;
    int row0 = blk * 16;
    int b  = blk >> 6;
    int n0 = row0 & 1023;

    {
        int sr = t >> 4, sc = (t & 15) * 16;
        const float* xp = x + (long)(row0 + sr) * INF_ + sc;
        float4 v0 = ((const float4*)xp)[0];
        float4 v1 = ((const float4*)xp)[1];
        float4 v2 = ((const float4*)xp)[2];
        float4 v3 = ((const float4*)xp)[3];
        ushort4 u0 = {f2bf(v0.x), f2bf(v0.y), f2bf(v0.z), f2bf(v0.w)};
        ushort4 u1 = {f2bf(v1.x), f2bf(v1.y), f2bf(v1.z), f2bf(v1.w)};
        ushort4 u2 = {f2bf(v2.x), f2bf(v2.y), f2bf(v2.z), f2bf(v2.w)};
        ushort4 u3 = {f2bf(v3.x), f2bf(v3.y), f2bf(v3.z), f2bf(v3.w)};
        *(ushort4*)&xls[sr][sc]      = u0;
        *(ushort4*)&xls[sr][sc + 4]  = u1;
        *(ushort4*)&xls[sr][sc + 8]  = u2;
        *(ushort4*)&xls[sr][sc + 12] = u3;
    }
    __syncthreads();

    int wave = t >> 6, lane = t & 63, quad = lane >> 4, l15 = lane & 15;
    f32x4 acc[4];
    #pragma unroll
    for (int i = 0; i < 4; i++) acc[i] = (f32x4){0.f, 0.f, 0.f, 0.f};

    #pragma unroll
    for (int ks = 0; ks < 8; ks++) {
        short8 af = *(const short8*)&xls[l15][ks * 32 + quad * 8];
        #pragma unroll
        for (int nt = 0; nt < 4; nt++) {
            short8 bf = *(const short8*)(wswz +
                ((long)((ks * 16 + wave * 4 + nt) * 64 + lane)) * 8);
            acc[nt] = __builtin_amdgcn_mfma_f32_16x16x32_bf16(af, bf, acc[nt], 0, 0, 0);
        }
    }

    // hswz store (B-frag order for k_attn)
    int q0 = (quad & 1) * 4;
    int qd = ((row0 & 31) + quad * 4) >> 3;
    long bj32 = row0 >> 5;
    #pragma unroll
    for (int nt = 0; nt < 4; nt++) {
        int dg = wave * 4 + nt;
        long idx8 = (bj32 * 16 + dg) * 64 + qd * 16 + l15;
        ushort4 o = {f2bf(acc[nt][0]), f2bf(acc[nt][1]),
                     f2bf(acc[nt][2]), f2bf(acc[nt][3])};
        *(ushort4*)&hswz[idx8 * 8 + q0] = o;
    }

    // fused scores -> row factor + exp pairs, pre-scaled by log2(e)
    float as_[4], ad_[4];
    #pragma unroll
    for (int nt = 0; nt < 4; nt++) {
        int d = nt * 16 + l15;
        as_[nt] = a[d * NH_ + wave];
        ad_[nt] = a[(64 + d) * NH_ + wave];
    }
    #pragma unroll
    for (int r = 0; r < 4; r++) {
        float ps = acc[0][r] * as_[0] + acc[1][r] * as_[1]
                 + acc[2][r] * as_[2] + acc[3][r] * as_[3];
        float pd = acc[0][r] * ad_[0] + acc[1][r] * ad_[1]
                 + acc[2][r] * ad_[2] + acc[3][r] * ad_[3];
        #pragma unroll
        for (int m = 1; m < 16; m <<= 1) {
            ps += __shfl_xor(ps, m);
            pd += __shfl_xor(pd, m);
        }
        if (l15 == 0) {
            int row = n0 + quad * 4 + r;
            float s1 = ps * L2E, s2 = pd * L2E;
            esr[((long)b * NH_ + wave) * N_ + row] = __builtin_exp2f(-0.8f * s1);
            edst[((long)b * NH_ + wave) * N_ + row] =
                make_float2(__builtin_exp2f(s2), __builtin_exp2f(0.2f * s2));
        }
    }
}

// ---------------------------------------------------------------------------
// Kernel C: masked softmax + MFMA aggregate, DOUBLE-BUFFERED LDS STAGING.
// R1/R5/R6 post-mortems: latency-bound on in-loop L2 reads of hswz; TLP
// (R2/R6) doesn't fix it. Fix = global_load_lds async staging (m97 lever):
// hswz chunk for one jc (32 j x 256 d bf16 = 16KB) is CONTIGUOUS in B-frag
// order -> linear glds into LDS, loads for jc+1 in flight during compute
// of jc, one barrier per jc.
// grid = 512 blocks (16 b x 32 ig, XCD-swizzled) x 512 thr = 8 waves =
// 4 heads (hh) x 2 i-strips (sw). Each wave owns (hh, 16 rows) over ALL
// 1024 j -> NO cross-wave combine, direct normalize+store epilogue.
// LDS: 2 x 16KB hbuf + mtab = 33KB -> 2 blocks/CU co-resident (grid-
// capped; latency hidden by staging MLP, not TLP).
// Weight pipeline: w = fmax(D1_j, r_i*D2_j) (E1 cancels in softmax),
// packed via v_cvt_pk_bf16_f32, masked by 16-entry LDS nibble table.
// ---------------------------------------------------------------------------
__global__ __launch_bounds__(512, 4) void k_attn(
    const unsigned int* __restrict__ pb, const unsigned short* __restrict__ hswz,
    const float* __restrict__ esr, const float2* __restrict__ edst,
    float* __restrict__ out)
{
    __shared__ uint2 mtab[16];
    __shared__ unsigned short hbuf0[8192];   // 16 KB
    __shared__ unsigned short hbuf1[8192];   // 16 KB

    int t = threadIdx.x;
    int bid = blockIdx.x;
    int swz = (bid & 7) * 64 + (bid >> 3);   // bijective (512 % 8 == 0)
    int b  = swz >> 5, ig = swz & 31;
    int i0 = ig * 32;
    int wave = t >> 6, lane = t & 63, quad = lane >> 4, l15 = lane & 15;
    int hh = wave & 3, sw = wave >> 2;       // head, i-strip

    if (t < 16) {
        int k = t;
        unsigned int w0 = ((k & 1) ? 0xffffu : 0u) | ((k & 2) ? 0xffff0000u : 0u);
        unsigned int w1 = ((k & 4) ? 0xffffu : 0u) | ((k & 8) ? 0xffff0000u : 0u);
        mtab[k] = make_uint2(w0, w1);
    }

    int irow = i0 + sw * 16 + l15;
    float r0 = esr[((long)(b * NH_ + hh)) * N_ + irow];
    const float2* edp = edst + ((long)(b * NH_ + hh)) * N_;
    const unsigned int* pbrow = pb + ((((long)b << 10) + irow) << 5);
    const unsigned short* hsrc = hswz + (((long)b * 32) << 13);  // 16KB/jc chunks

    f32x4 acc[4], dn;
    #pragma unroll
    for (int i = 0; i < 4; i++) acc[i] = (f32x4){0.f, 0.f, 0.f, 0.f};
    dn = (f32x4){0.f, 0.f, 0.f, 0.f};
    short8 ones;
    #pragma unroll
    for (int i = 0; i < 8; i++) ones[i] = (short)0x3F80;   // bf16 1.0

    int shq = quad * 8;

    // stage jc chunk into BUF: 8 waves x 2 x (64 lanes x 16B) = 16 KB linear
    #define STAGE(BUF, JC) { \
        const unsigned short* g = hsrc + (((long)(JC)) << 13); \
        glds16(g + (wave * 128 + lane) * 8,      &BUF[wave * 1024]); \
        glds16(g + (wave * 128 + 64 + lane) * 8, &BUF[wave * 1024 + 512]); }

    #define COMPUTE(JC, BUF) { \
        unsigned int m0 = (pbrow[(JC)] >> shq) & 0xffu; \
        const float4* ej = (const float4*)(edp + (JC) * 32 + quad * 8); \
        union { unsigned int u[4]; short8 s; } p0; \
        _Pragma("unroll") \
        for (int qp = 0; qp < 4; qp++) { \
            float4 d = ej[qp]; \
            p0.u[qp] = cvt_pk_bf16(fmaxf(d.x, r0 * d.y), fmaxf(d.z, r0 * d.w)); \
        } \
        uint2 ma = mtab[m0 & 15u], mb = mtab[m0 >> 4]; \
        p0.u[0] &= ma.x; p0.u[1] &= ma.y; p0.u[2] &= mb.x; p0.u[3] &= mb.y; \
        _Pragma("unroll") \
        for (int idt = 0; idt < 4; idt++) { \
            short8 bf = *(const short8*)&BUF[(hh * 4 + idt) * 512 + lane * 8]; \
            acc[idt] = __builtin_amdgcn_mfma_f32_16x16x32_bf16(p0.s, bf, acc[idt], 0, 0, 0); \
        } \
        dn = __builtin_amdgcn_mfma_f32_16x16x32_bf16(p0.s, ones, dn, 0, 0, 0); }

    STAGE(hbuf0, 0);
    for (int jc = 0; jc < 32; jc += 2) {
        __syncthreads();                       // hbuf0 (jc) staged; prev compute of hbuf1 done
        STAGE(hbuf1, jc + 1);                  // in flight during compute below
        COMPUTE(jc, hbuf0);
        __syncthreads();                       // hbuf1 (jc+1) staged; compute of hbuf0 done
        if (jc + 2 < 32) STAGE(hbuf0, jc + 2);
        COMPUTE(jc + 1, hbuf1);
    }
    #undef STAGE
    #undef COMPUTE

    // epilogue: per-wave normalize + store (no cross-wave combine)
    float inv[4];
    #pragma unroll
    for (int r = 0; r < 4; r++) inv[r] = 1.0f / dn[r];
    #pragma unroll
    for (int idt = 0; idt < 4; idt++) {
        int col = hh * 64 + idt * 16 + l15;
        #pragma unroll
        for (int r = 0; r < 4; r++) {
            long row_g = (long)b * N_ + i0 + sw * 16 + quad * 4 + r;
            out[row_g * HD_ + col] = acc[idt][r] * inv[r];
        }
    }
}

extern "C" void kernel_launch(void* const* d_in, const int* in_sizes, int n_in,
                              void* d_out, int out_size, void* d_ws, size_t ws_size,
                              hipStream_t stream) {
    const float* x   = (const float*)d_in[0];
    const int*   adj = (const int*)d_in[1];
    const float* W   = (const float*)d_in[2];
    const float* a   = (const float*)d_in[3];
    float* out = (float*)d_out;

    unsigned int* pb      = (unsigned int*)d_ws;                       // 2 MB
    unsigned short* hswz  = (unsigned short*)(pb + 524288);            // 8 MB
    unsigned short* wswz  = hswz + (long)B_ * N_ * HD_;                // 128 KB
    float* esr   = (float*)(wswz + INF_ * HD_);                        // 256 KB
    float2* edst = (float2*)(esr + (long)B_ * NH_ * N_);               // 512 KB

    k_prep<<<2080, 256, 0, stream>>>(adj, W, pb, wswz);
    k_gemm_h<<<1024, 256, 0, stream>>>(x, a, wswz, hswz, esr, edst);
    k_attn<<<512, 512, 0, stream>>>(pb, hswz, esr, edst, out);
}

// Round 8
// 153.714 us; speedup vs baseline: 1.0891x; 1.0891x over previous
//
#include <hip/hip_runtime.h>
#include <hip/hip_bf16.h>

#define B_   16
#define N_   1024
#define INF_ 256
#define NH_  4
#define HD_  256
#define L2E  1.4426950408889634f

typedef __attribute__((ext_vector_type(8))) short short8;
typedef __attribute__((ext_vector_type(4))) float f32x4;

__device__ __forceinline__ float bf2f(unsigned short u) {
    union { unsigned int i; float f; } v; v.i = ((unsigned int)u) << 16; return v.f;
}
__device__ __forceinline__ unsigned short f2bf(float f) {
    union { float f; unsigned int i; } v; v.f = f;
    unsigned int x = v.i;
    return (unsigned short)((x + 0x7fffu + ((x >> 16) & 1u)) >> 16);
}
// pack 2 f32 -> 2 bf16 in one op (low16 = lo, high16 = hi); no builtin on gfx950
__device__ __forceinline__ unsigned int cvt_pk_bf16(float lo, float hi) {
    unsigned int r;
    asm("v_cvt_pk_bf16_f32 %0, %1, %2" : "=v"(r) : "v"(lo), "v"(hi));
    return r;
}

// ---------------------------------------------------------------------------
// Kernel PREP (fused):
//  blocks [0,2048): pack adj -> TRANSPOSED bitmask pb[word][grow] (uint32,
//    bit p of word w = adj[row][w*32+p]). Transposed so k_attn's per-jc
//    mask load is lane-coalesced (4B consecutive per lane) instead of a
//    128B-stride 16-line gather. Writes here are scattered 4B stores but
//    pb is only 2MB total — L3 merges the partial lines.
//  blocks [2048,2080): W fp32 -> wswz bf16 in MFMA B-frag order.
// ---------------------------------------------------------------------------
__global__ __launch_bounds__(256) void k_prep(const int* __restrict__ adj,
                                              const float* __restrict__ W,
                                              unsigned int* __restrict__ pb,
                                              unsigned short* __restrict__ wswz)
{
    int bx = blockIdx.x, t = threadIdx.x;
    if (bx < 2048) {
        int wave = t >> 6, lane = t & 63;
        int row = bx * 8 + wave * 2 + (lane >> 5);   // [0, 16384)
        int w   = lane & 31;
        const int4* ar = (const int4*)(adj + ((long)row << 10) + w * 32);
        unsigned int u = 0;
        #pragma unroll
        for (int k = 0; k < 8; k++) {
            int4 a = ar[k];
            u |= ((unsigned)a.x) << (4 * k);
            u |= ((unsigned)a.y) << (4 * k + 1);
            u |= ((unsigned)a.z) << (4 * k + 2);
            u |= ((unsigned)a.w) << (4 * k + 3);
        }
        pb[((long)w << 14) + row] = u;               // TRANSPOSED: [word][grow]
    } else {
        int slot = (bx - 2048) * 256 + t;
        int kstep = slot >> 10;
        int nt    = (slot >> 6) & 15;
        int lane  = slot & 63;
        int k0 = kstep * 32 + (lane >> 4) * 8;
        int n  = nt * 16 + (lane & 15);
        ushort4 o0, o1;
        o0.x = f2bf(W[(k0 + 0) * HD_ + n]);
        o0.y = f2bf(W[(k0 + 1) * HD_ + n]);
        o0.z = f2bf(W[(k0 + 2) * HD_ + n]);
        o0.w = f2bf(W[(k0 + 3) * HD_ + n]);
        o1.x = f2bf(W[(k0 + 4) * HD_ + n]);
        o1.y = f2bf(W[(k0 + 5) * HD_ + n]);
        o1.z = f2bf(W[(k0 + 6) * HD_ + n]);
        o1.w = f2bf(W[(k0 + 7) * HD_ + n]);
        *(ushort4*)&wswz[(long)slot * 8]     = o0;
        *(ushort4*)&wswz[(long)slot * 8 + 4] = o1;
    }
}

// ---------------------------------------------------------------------------
// Kernel A: h = x @ W via MFMA, W-frags from L2 in-loop.
// Block = 256 thr = 4 waves (one head each), 16 rows. grid = 1024.
// Emits hswz (B-frag order bf16) + per-row factors:
//   esr[(b,h,i)]  = exp2(-0.8*ss)   (E1 cancels in softmax -> dropped)
//   edst[(b,h,j)] = {exp2(sd), exp2(0.2*sd)}
// Attention weight (unnormalized) = max(D1_j, r_i*D2_j).
// ---------------------------------------------------------------------------
__global__ __launch_bounds__(256) void k_gemm_h(
    const float* __restrict__ x, const float* __restrict__ a,
    const unsigned short* __restrict__ wswz,
    unsigned short* __restrict__ hswz,
    float* __restrict__ esr, float2* __restrict__ edst)
{
    __shared__ unsigned short xls[16][264];
    int t = threadIdx.x;
    int blk = blockIdx.x;
    int row0 = blk * 16;
    int b  = blk >> 6;
    int n0 = row0 & 1023;

    {
        int sr = t >> 4, sc = (t & 15) * 16;
        const float* xp = x + (long)(row0 + sr) * INF_ + sc;
        float4 v0 = ((const float4*)xp)[0];
        float4 v1 = ((const float4*)xp)[1];
        float4 v2 = ((const float4*)xp)[2];
        float4 v3 = ((const float4*)xp)[3];
        ushort4 u0 = {f2bf(v0.x), f2bf(v0.y), f2bf(v0.z), f2bf(v0.w)};
        ushort4 u1 = {f2bf(v1.x), f2bf(v1.y), f2bf(v1.z), f2bf(v1.w)};
        ushort4 u2 = {f2bf(v2.x), f2bf(v2.y), f2bf(v2.z), f2bf(v2.w)};
        ushort4 u3 = {f2bf(v3.x), f2bf(v3.y), f2bf(v3.z), f2bf(v3.w)};
        *(ushort4*)&xls[sr][sc]      = u0;
        *(ushort4*)&xls[sr][sc + 4]  = u1;
        *(ushort4*)&xls[sr][sc + 8]  = u2;
        *(ushort4*)&xls[sr][sc + 12] = u3;
    }
    __syncthreads();

    int wave = t >> 6, lane = t & 63, quad = lane >> 4, l15 = lane & 15;
    f32x4 acc[4];
    #pragma unroll
    for (int i = 0; i < 4; i++) acc[i] = (f32x4){0.f, 0.f, 0.f, 0.f};

    #pragma unroll
    for (int ks = 0; ks < 8; ks++) {
        short8 af = *(const short8*)&xls[l15][ks * 32 + quad * 8];
        #pragma unroll
        for (int nt = 0; nt < 4; nt++) {
            short8 bf = *(const short8*)(wswz +
                ((long)((ks * 16 + wave * 4 + nt) * 64 + lane)) * 8);
            acc[nt] = __builtin_amdgcn_mfma_f32_16x16x32_bf16(af, bf, acc[nt], 0, 0, 0);
        }
    }

    // hswz store (B-frag order for k_attn)
    int q0 = (quad & 1) * 4;
    int qd = ((row0 & 31) + quad * 4) >> 3;
    long bj32 = row0 >> 5;
    #pragma unroll
    for (int nt = 0; nt < 4; nt++) {
        int dg = wave * 4 + nt;
        long idx8 = (bj32 * 16 + dg) * 64 + qd * 16 + l15;
        ushort4 o = {f2bf(acc[nt][0]), f2bf(acc[nt][1]),
                     f2bf(acc[nt][2]), f2bf(acc[nt][3])};
        *(ushort4*)&hswz[idx8 * 8 + q0] = o;
    }

    // fused scores -> row factor + exp pairs, pre-scaled by log2(e)
    float as_[4], ad_[4];
    #pragma unroll
    for (int nt = 0; nt < 4; nt++) {
        int d = nt * 16 + l15;
        as_[nt] = a[d * NH_ + wave];
        ad_[nt] = a[(64 + d) * NH_ + wave];
    }
    #pragma unroll
    for (int r = 0; r < 4; r++) {
        float ps = acc[0][r] * as_[0] + acc[1][r] * as_[1]
                 + acc[2][r] * as_[2] + acc[3][r] * as_[3];
        float pd = acc[0][r] * ad_[0] + acc[1][r] * ad_[1]
                 + acc[2][r] * ad_[2] + acc[3][r] * ad_[3];
        #pragma unroll
        for (int m = 1; m < 16; m <<= 1) {
            ps += __shfl_xor(ps, m);
            pd += __shfl_xor(pd, m);
        }
        if (l15 == 0) {
            int row = n0 + quad * 4 + r;
            float s1 = ps * L2E, s2 = pd * L2E;
            esr[((long)b * NH_ + wave) * N_ + row] = __builtin_exp2f(-0.8f * s1);
            edst[((long)b * NH_ + wave) * N_ + row] =
                make_float2(__builtin_exp2f(s2), __builtin_exp2f(0.2f * s2));
        }
    }
}

// ---------------------------------------------------------------------------
// Kernel C: masked softmax + MFMA aggregate. R5 base (best measured:
// R1 per-wave shape — VGPR 56, 2 i-strips sharing every B-frag load —
// + XCD-bijective swizzle, FETCH 35->5.5MB) with ONE change: pb is now
// TRANSPOSED [word][grow], so the per-jc mask loads are lane-coalesced
// (1 cache line per load instead of a 16-line 128B-stride gather). The
// gathers were in the mask->weight->MFMA dependency chain and hammered
// the TA/L1 fill path (2 gathers/jc x 16 jc x 16 waves/CU).
// grid = 512 blocks x 512 thr = 8 waves (hh=wave&3, jh=wave>>2 in {0,1}).
// __launch_bounds__(512,4) ONLY — min-waves>=8 forces VGPR<=32 and either
// kills MLP (R2) or spills (R3); macro-shrunk bodies also collapse to
// VGPR 32 (R7). Keep the fat straight-line loop body.
// Weight pipeline: w = fmax(D1_j, r_i*D2_j) (E1 cancels in softmax),
// packed via v_cvt_pk_bf16_f32, masked by 16-entry LDS nibble table.
// ---------------------------------------------------------------------------
__global__ __launch_bounds__(512, 4) void k_attn(
    const unsigned int* __restrict__ pb, const unsigned short* __restrict__ hswz,
    const float* __restrict__ esr, const float2* __restrict__ edst,
    float* __restrict__ out)
{
    __shared__ uint2 mtab[16];
    __shared__ float accb[4][2][64][20];   // [hh][strip][lane][16 acc + 4 den]

    int t = threadIdx.x;
    int bid = blockIdx.x;
    int swz = (bid & 7) * 64 + (bid >> 3);   // bijective (512 % 8 == 0)
    int b  = swz >> 5, ig = swz & 31;
    int i0 = ig * 32;
    int wave = t >> 6, lane = t & 63, quad = lane >> 4, l15 = lane & 15;
    int hh = wave & 3, jh = wave >> 2;

    if (t < 16) {
        int k = t;
        unsigned int w0 = ((k & 1) ? 0xffffu : 0u) | ((k & 2) ? 0xffff0000u : 0u);
        unsigned int w1 = ((k & 4) ? 0xffffu : 0u) | ((k & 8) ? 0xffff0000u : 0u);
        mtab[k] = make_uint2(w0, w1);
    }
    __syncthreads();

    float r0 = esr[((long)(b * NH_ + hh)) * N_ + i0 + l15];
    float r1 = esr[((long)(b * NH_ + hh)) * N_ + i0 + 16 + l15];
    const float2* edp = edst + ((long)(b * NH_ + hh)) * N_ + jh * 512;
    // transposed pb: word W = jh*16+jc lives at pb[W*16384 + grow]
    const unsigned int* pbw = pb + (((long)(jh * 16)) << 14) + (b << 10) + i0 + l15;

    f32x4 acc0[4], acc1[4], dn0, dn1;
    #pragma unroll
    for (int i = 0; i < 4; i++) {
        acc0[i] = (f32x4){0.f, 0.f, 0.f, 0.f};
        acc1[i] = (f32x4){0.f, 0.f, 0.f, 0.f};
    }
    dn0 = (f32x4){0.f, 0.f, 0.f, 0.f};
    dn1 = (f32x4){0.f, 0.f, 0.f, 0.f};
    short8 ones;
    #pragma unroll
    for (int i = 0; i < 8; i++) ones[i] = (short)0x3F80;   // bf16 1.0

    int shq = quad * 8;

    #pragma unroll 4
    for (int jc = 0; jc < 16; jc++) {
        unsigned int m0 = (pbw[((long)jc << 14)] >> shq) & 0xffu;        // strip0, coalesced
        unsigned int m1 = (pbw[((long)jc << 14) + 16] >> shq) & 0xffu;   // strip1, coalesced
        const float4* ej = (const float4*)(edp + jc * 32 + quad * 8);

        union { unsigned int u[4]; short8 s; } p0, p1;
        #pragma unroll
        for (int qp = 0; qp < 4; qp++) {
            float4 d = ej[qp];   // {D1_j, D2_j, D1_j', D2_j'} for j=2qp, 2qp+1
            p0.u[qp] = cvt_pk_bf16(fmaxf(d.x, r0 * d.y), fmaxf(d.z, r0 * d.w));
            p1.u[qp] = cvt_pk_bf16(fmaxf(d.x, r1 * d.y), fmaxf(d.z, r1 * d.w));
        }
        uint2 ma0 = mtab[m0 & 15u], mb0 = mtab[m0 >> 4];
        uint2 ma1 = mtab[m1 & 15u], mb1 = mtab[m1 >> 4];
        p0.u[0] &= ma0.x; p0.u[1] &= ma0.y; p0.u[2] &= mb0.x; p0.u[3] &= mb0.y;
        p1.u[0] &= ma1.x; p1.u[1] &= ma1.y; p1.u[2] &= mb1.x; p1.u[3] &= mb1.y;

        long s8 = ((long)(b * 32 + jh * 16 + jc)) * 1024;
        #pragma unroll
        for (int idt = 0; idt < 4; idt++) {
            short8 bf = *(const short8*)(hswz + (s8 + (hh * 4 + idt) * 64 + lane) * 8);
            acc0[idt] = __builtin_amdgcn_mfma_f32_16x16x32_bf16(p0.s, bf, acc0[idt], 0, 0, 0);
            acc1[idt] = __builtin_amdgcn_mfma_f32_16x16x32_bf16(p1.s, bf, acc1[idt], 0, 0, 0);
        }
        dn0 = __builtin_amdgcn_mfma_f32_16x16x32_bf16(p0.s, ones, dn0, 0, 0, 0);
        dn1 = __builtin_amdgcn_mfma_f32_16x16x32_bf16(p1.s, ones, dn1, 0, 0, 0);
    }

    if (jh == 1) {
        #pragma unroll
        for (int idt = 0; idt < 4; idt++) {
            *(f32x4*)&accb[hh][0][lane][idt * 4] = acc0[idt];
            *(f32x4*)&accb[hh][1][lane][idt * 4] = acc1[idt];
        }
        *(f32x4*)&accb[hh][0][lane][16] = dn0;
        *(f32x4*)&accb[hh][1][lane][16] = dn1;
    }
    __syncthreads();

    if (jh == 0) {
        f32x4 od0 = *(const f32x4*)&accb[hh][0][lane][16];
        f32x4 od1 = *(const f32x4*)&accb[hh][1][lane][16];
        float inv0[4], inv1[4];
        #pragma unroll
        for (int r = 0; r < 4; r++) {
            inv0[r] = 1.0f / (dn0[r] + od0[r]);
            inv1[r] = 1.0f / (dn1[r] + od1[r]);
        }
        #pragma unroll
        for (int idt = 0; idt < 4; idt++) {
            f32x4 o0 = *(const f32x4*)&accb[hh][0][lane][idt * 4];
            f32x4 o1 = *(const f32x4*)&accb[hh][1][lane][idt * 4];
            int col = hh * 64 + idt * 16 + l15;
            #pragma unroll
            for (int r = 0; r < 4; r++) {
                long row_g = (long)b * N_ + i0 + quad * 4 + r;
                out[row_g * HD_ + col] = (acc0[idt][r] + o0[r]) * inv0[r];
                out[(row_g + 16) * HD_ + col] = (acc1[idt][r] + o1[r]) * inv1[r];
            }
        }
    }
}

extern "C" void kernel_launch(void* const* d_in, const int* in_sizes, int n_in,
                              void* d_out, int out_size, void* d_ws, size_t ws_size,
                              hipStream_t stream) {
    const float* x   = (const float*)d_in[0];
    const int*   adj = (const int*)d_in[1];
    const float* W   = (const float*)d_in[2];
    const float* a   = (const float*)d_in[3];
    float* out = (float*)d_out;

    unsigned int* pb      = (unsigned int*)d_ws;                       // 2 MB
    unsigned short* hswz  = (unsigned short*)(pb + 524288);            // 8 MB
    unsigned short* wswz  = hswz + (long)B_ * N_ * HD_;                // 128 KB
    float* esr   = (float*)(wswz + INF_ * HD_);                        // 256 KB
    float2* edst = (float2*)(esr + (long)B_ * NH_ * N_);               // 512 KB

    k_prep<<<2080, 256, 0, stream>>>(adj, W, pb, wswz);
    k_gemm_h<<<1024, 256, 0, stream>>>(x, a, wswz, hswz, esr, edst);
    k_attn<<<512, 512, 0, stream>>>(pb, hswz, esr, edst, out);
}

// Round 9
// 149.482 us; speedup vs baseline: 1.1200x; 1.0283x over previous
//
#include <hip/hip_runtime.h>
#include <hip/hip_bf16.h>

#define B_   16
#define N_   1024
#define INF_ 256
#define NH_  4
#define HD_  256
#define L2E  1.4426950408889634f

typedef __attribute__((ext_vector_type(8))) short short8;
typedef __attribute__((ext_vector_type(4))) float f32x4;

__device__ __forceinline__ float bf2f(unsigned short u) {
    union { unsigned int i; float f; } v; v.i = ((unsigned int)u) << 16; return v.f;
}
__device__ __forceinline__ unsigned short f2bf(float f) {
    union { float f; unsigned int i; } v; v.f = f;
    unsigned int x = v.i;
    return (unsigned short)((x + 0x7fffu + ((x >> 16) & 1u)) >> 16);
}
// pack 2 f32 -> 2 bf16 in one op (low16 = lo, high16 = hi); no builtin on gfx950
__device__ __forceinline__ unsigned int cvt_pk_bf16(float lo, float hi) {
    unsigned int r;
    asm("v_cvt_pk_bf16_f32 %0, %1, %2" : "=v"(r) : "v"(lo), "v"(hi));
    return r;
}

// ---------------------------------------------------------------------------
// Kernel PREP (fused):
//  blocks [0,2048): pack adj -> TRANSPOSED bitmask pb[word][grow] (uint32,
//    bit p of word w = adj[row][w*32+p]); k_attn mask loads are coalesced.
//  blocks [2048,2080): W fp32 -> wswz bf16 in MFMA B-frag order.
// ---------------------------------------------------------------------------
__global__ __launch_bounds__(256) void k_prep(const int* __restrict__ adj,
                                              const float* __restrict__ W,
                                              unsigned int* __restrict__ pb,
                                              unsigned short* __restrict__ wswz)
{
    int bx = blockIdx.x, t = threadIdx.x;
    if (bx < 2048) {
        int wave = t >> 6, lane = t & 63;
        int row = bx * 8 + wave * 2 + (lane >> 5);   // [0, 16384)
        int w   = lane & 31;
        const int4* ar = (const int4*)(adj + ((long)row << 10) + w * 32);
        unsigned int u = 0;
        #pragma unroll
        for (int k = 0; k < 8; k++) {
            int4 a = ar[k];
            u |= ((unsigned)a.x) << (4 * k);
            u |= ((unsigned)a.y) << (4 * k + 1);
            u |= ((unsigned)a.z) << (4 * k + 2);
            u |= ((unsigned)a.w) << (4 * k + 3);
        }
        pb[((long)w << 14) + row] = u;               // TRANSPOSED: [word][grow]
    } else {
        int slot = (bx - 2048) * 256 + t;
        int kstep = slot >> 10;
        int nt    = (slot >> 6) & 15;
        int lane  = slot & 63;
        int k0 = kstep * 32 + (lane >> 4) * 8;
        int n  = nt * 16 + (lane & 15);
        ushort4 o0, o1;
        o0.x = f2bf(W[(k0 + 0) * HD_ + n]);
        o0.y = f2bf(W[(k0 + 1) * HD_ + n]);
        o0.z = f2bf(W[(k0 + 2) * HD_ + n]);
        o0.w = f2bf(W[(k0 + 3) * HD_ + n]);
        o1.x = f2bf(W[(k0 + 4) * HD_ + n]);
        o1.y = f2bf(W[(k0 + 5) * HD_ + n]);
        o1.z = f2bf(W[(k0 + 6) * HD_ + n]);
        o1.w = f2bf(W[(k0 + 7) * HD_ + n]);
        *(ushort4*)&wswz[(long)slot * 8]     = o0;
        *(ushort4*)&wswz[(long)slot * 8 + 4] = o1;
    }
}

// ---------------------------------------------------------------------------
// Kernel A: h = x @ W via MFMA, W-frags from L2 in-loop.
// Block = 256 thr = 4 waves (one head each), 16 rows. grid = 1024.
// Emits hswz (B-frag order bf16) + per-row factors:
//   esr[(b,h,i)]  = exp2(-0.8*ss)   (E1 cancels in softmax -> dropped)
//   edst[(b,h,j)] = {exp2(sd), exp2(0.2*sd)}
// Attention weight (unnormalized) = max(D1_j, r_i*D2_j).
// ---------------------------------------------------------------------------
__global__ __launch_bounds__(256) void k_gemm_h(
    const float* __restrict__ x, const float* __restrict__ a,
    const unsigned short* __restrict__ wswz,
    unsigned short* __restrict__ hswz,
    float* __restrict__ esr, float2* __restrict__ edst)
{
    __shared__ unsigned short xls[16][264];
    int t = threadIdx.x;
    int blk = blockIdx.x;
    int row0 = blk * 16;
    int b  = blk >> 6;
    int n0 = row0 & 1023;

    {
        int sr = t >> 4, sc = (t & 15) * 16;
        const float* xp = x + (long)(row0 + sr) * INF_ + sc;
        float4 v0 = ((const float4*)xp)[0];
        float4 v1 = ((const float4*)xp)[1];
        float4 v2 = ((const float4*)xp)[2];
        float4 v3 = ((const float4*)xp)[3];
        ushort4 u0 = {f2bf(v0.x), f2bf(v0.y), f2bf(v0.z), f2bf(v0.w)};
        ushort4 u1 = {f2bf(v1.x), f2bf(v1.y), f2bf(v1.z), f2bf(v1.w)};
        ushort4 u2 = {f2bf(v2.x), f2bf(v2.y), f2bf(v2.z), f2bf(v2.w)};
        ushort4 u3 = {f2bf(v3.x), f2bf(v3.y), f2bf(v3.z), f2bf(v3.w)};
        *(ushort4*)&xls[sr][sc]      = u0;
        *(ushort4*)&xls[sr][sc + 4]  = u1;
        *(ushort4*)&xls[sr][sc + 8]  = u2;
        *(ushort4*)&xls[sr][sc + 12] = u3;
    }
    __syncthreads();

    int wave = t >> 6, lane = t & 63, quad = lane >> 4, l15 = lane & 15;
    f32x4 acc[4];
    #pragma unroll
    for (int i = 0; i < 4; i++) acc[i] = (f32x4){0.f, 0.f, 0.f, 0.f};

    #pragma unroll
    for (int ks = 0; ks < 8; ks++) {
        short8 af = *(const short8*)&xls[l15][ks * 32 + quad * 8];
        #pragma unroll
        for (int nt = 0; nt < 4; nt++) {
            short8 bf = *(const short8*)(wswz +
                ((long)((ks * 16 + wave * 4 + nt) * 64 + lane)) * 8);
            acc[nt] = __builtin_amdgcn_mfma_f32_16x16x32_bf16(af, bf, acc[nt], 0, 0, 0);
        }
    }

    // hswz store (B-frag order for k_attn)
    int q0 = (quad & 1) * 4;
    int qd = ((row0 & 31) + quad * 4) >> 3;
    long bj32 = row0 >> 5;
    #pragma unroll
    for (int nt = 0; nt < 4; nt++) {
        int dg = wave * 4 + nt;
        long idx8 = (bj32 * 16 + dg) * 64 + qd * 16 + l15;
        ushort4 o = {f2bf(acc[nt][0]), f2bf(acc[nt][1]),
                     f2bf(acc[nt][2]), f2bf(acc[nt][3])};
        *(ushort4*)&hswz[idx8 * 8 + q0] = o;
    }

    // fused scores -> row factor + exp pairs, pre-scaled by log2(e)
    float as_[4], ad_[4];
    #pragma unroll
    for (int nt = 0; nt < 4; nt++) {
        int d = nt * 16 + l15;
        as_[nt] = a[d * NH_ + wave];
        ad_[nt] = a[(64 + d) * NH_ + wave];
    }
    #pragma unroll
    for (int r = 0; r < 4; r++) {
        float ps = acc[0][r] * as_[0] + acc[1][r] * as_[1]
                 + acc[2][r] * as_[2] + acc[3][r] * as_[3];
        float pd = acc[0][r] * ad_[0] + acc[1][r] * ad_[1]
                 + acc[2][r] * ad_[2] + acc[3][r] * ad_[3];
        #pragma unroll
        for (int m = 1; m < 16; m <<= 1) {
            ps += __shfl_xor(ps, m);
            pd += __shfl_xor(pd, m);
        }
        if (l15 == 0) {
            int row = n0 + quad * 4 + r;
            float s1 = ps * L2E, s2 = pd * L2E;
            esr[((long)b * NH_ + wave) * N_ + row] = __builtin_exp2f(-0.8f * s1);
            edst[((long)b * NH_ + wave) * N_ + row] =
                make_float2(__builtin_exp2f(s2), __builtin_exp2f(0.2f * s2));
        }
    }
}

// ---------------------------------------------------------------------------
// Kernel C: masked softmax + MFMA aggregate — HIGH-REUSE BLOCKS.
// Theory (R8 post-mortem): k_attn is bound by per-CU L1/TCP line traffic —
// every 32-row block re-read the whole 512KB hswz[b], so per-CU traffic
// was ~1MB (19K cache lines). Fix: one block = one (b, head, 256 rows):
// per-block hswz slice = 128KB read ONCE -> total hswz traffic 256->32MB,
// per-CU 1MB->128KB (8x).
// grid = 256 blocks (16 b x 4 head x 4 rowgroups, XCD-swizzled: 2 b/XCD
// -> L2-resident) x 1024 thr = 16 waves = 16 strips of 16 rows. Per-wave
// body is the PROVEN R6/R8 shape (~60 VGPR, 4+1 MFMA per jc, fat
// straight-line code). No jh split -> no cross-wave combine, no accb, no
// loop barriers. edst head-slice (8KB) staged once to LDS -> per-jc
// dependency chain has only coalesced hswz + pb loads.
// __launch_bounds__(1024,4) = VGPR cap 128 (never min>=8: R2/R3 collapse).
// ---------------------------------------------------------------------------
__global__ __launch_bounds__(1024, 4) void k_attn(
    const unsigned int* __restrict__ pb, const unsigned short* __restrict__ hswz,
    const float* __restrict__ esr, const float2* __restrict__ edst,
    float* __restrict__ out)
{
    __shared__ float2 esb[1024];   // 8 KB: edst slice for (b, hh)
    __shared__ uint2 mtab[16];

    int t = threadIdx.x;
    int bid = blockIdx.x;
    int swz = (bid & 7) * 32 + (bid >> 3);   // bijective (256 % 8 == 0)
    int b  = swz >> 4;                        // 2 b per XCD -> L2-resident
    int hh = (swz >> 2) & 3;
    int rg = swz & 3;
    int row0 = rg * 256;

    int wave = t >> 6, lane = t & 63, quad = lane >> 4, l15 = lane & 15;

    esb[t] = edst[((long)(b * NH_ + hh)) * N_ + t];
    if (t < 16) {
        int k = t;
        unsigned int w0 = ((k & 1) ? 0xffffu : 0u) | ((k & 2) ? 0xffff0000u : 0u);
        unsigned int w1 = ((k & 4) ? 0xffffu : 0u) | ((k & 8) ? 0xffff0000u : 0u);
        mtab[k] = make_uint2(w0, w1);
    }
    __syncthreads();

    int irow = row0 + wave * 16 + l15;
    float r0 = esr[((long)(b * NH_ + hh)) * N_ + irow];
    // transposed pb: word jc at pb[jc*16384 + b*1024 + irow] (coalesced)
    const unsigned int* pbw = pb + ((long)b << 10) + irow;

    f32x4 acc[4], dn;
    #pragma unroll
    for (int i = 0; i < 4; i++) acc[i] = (f32x4){0.f, 0.f, 0.f, 0.f};
    dn = (f32x4){0.f, 0.f, 0.f, 0.f};
    short8 ones;
    #pragma unroll
    for (int i = 0; i < 8; i++) ones[i] = (short)0x3F80;   // bf16 1.0

    int shq = quad * 8;

    #pragma unroll 4
    for (int jc = 0; jc < 32; jc++) {
        unsigned int m0 = (pbw[((long)jc << 14)] >> shq) & 0xffu;
        const f32x4* ej = (const f32x4*)&esb[jc * 32 + quad * 8];

        union { unsigned int u[4]; short8 s; } p0;
        #pragma unroll
        for (int qp = 0; qp < 4; qp++) {
            f32x4 d = ej[qp];   // {D1_j, D2_j, D1_j', D2_j'} for j=2qp, 2qp+1
            p0.u[qp] = cvt_pk_bf16(fmaxf(d[0], r0 * d[1]), fmaxf(d[2], r0 * d[3]));
        }
        uint2 ma = mtab[m0 & 15u], mb = mtab[m0 >> 4];
        p0.u[0] &= ma.x; p0.u[1] &= ma.y; p0.u[2] &= mb.x; p0.u[3] &= mb.y;

        long s8 = ((long)(b * 32 + jc)) * 1024;
        #pragma unroll
        for (int idt = 0; idt < 4; idt++) {
            short8 bf = *(const short8*)(hswz + (s8 + (hh * 4 + idt) * 64 + lane) * 8);
            acc[idt] = __builtin_amdgcn_mfma_f32_16x16x32_bf16(p0.s, bf, acc[idt], 0, 0, 0);
        }
        dn = __builtin_amdgcn_mfma_f32_16x16x32_bf16(p0.s, ones, dn, 0, 0, 0);
    }

    // epilogue: per-wave normalize + store (no cross-wave combine at all)
    float inv[4];
    #pragma unroll
    for (int r = 0; r < 4; r++) inv[r] = 1.0f / dn[r];
    #pragma unroll
    for (int idt = 0; idt < 4; idt++) {
        int col = hh * 64 + idt * 16 + l15;
        #pragma unroll
        for (int r = 0; r < 4; r++) {
            long row_g = (long)b * N_ + row0 + wave * 16 + quad * 4 + r;
            out[row_g * HD_ + col] = acc[idt][r] * inv[r];
        }
    }
}

extern "C" void kernel_launch(void* const* d_in, const int* in_sizes, int n_in,
                              void* d_out, int out_size, void* d_ws, size_t ws_size,
                              hipStream_t stream) {
    const float* x   = (const float*)d_in[0];
    const int*   adj = (const int*)d_in[1];
    const float* W   = (const float*)d_in[2];
    const float* a   = (const float*)d_in[3];
    float* out = (float*)d_out;

    unsigned int* pb      = (unsigned int*)d_ws;                       // 2 MB
    unsigned short* hswz  = (unsigned short*)(pb + 524288);            // 8 MB
    unsigned short* wswz  = hswz + (long)B_ * N_ * HD_;                // 128 KB
    float* esr   = (float*)(wswz + INF_ * HD_);                        // 256 KB
    float2* edst = (float2*)(esr + (long)B_ * NH_ * N_);               // 512 KB

    k_prep<<<2080, 256, 0, stream>>>(adj, W, pb, wswz);
    k_gemm_h<<<1024, 256, 0, stream>>>(x, a, wswz, hswz, esr, edst);
    k_attn<<<256, 1024, 0, stream>>>(pb, hswz, esr, edst, out);
}

// Round 10
// 149.329 us; speedup vs baseline: 1.1211x; 1.0010x over previous
//
#include <hip/hip_runtime.h>
#include <hip/hip_bf16.h>

#define B_   16
#define N_   1024
#define INF_ 256
#define NH_  4
#define HD_  256
#define L2E  1.4426950408889634f

typedef __attribute__((ext_vector_type(8))) short short8;
typedef __attribute__((ext_vector_type(4))) float f32x4;

__device__ __forceinline__ float bf2f(unsigned short u) {
    union { unsigned int i; float f; } v; v.i = ((unsigned int)u) << 16; return v.f;
}
__device__ __forceinline__ unsigned short f2bf(float f) {
    union { float f; unsigned int i; } v; v.f = f;
    unsigned int x = v.i;
    return (unsigned short)((x + 0x7fffu + ((x >> 16) & 1u)) >> 16);
}
// pack 2 f32 -> 2 bf16 in one op (low16 = lo, high16 = hi); no builtin on gfx950
__device__ __forceinline__ unsigned int cvt_pk_bf16(float lo, float hi) {
    unsigned int r;
    asm("v_cvt_pk_bf16_f32 %0, %1, %2" : "=v"(r) : "v"(lo), "v"(hi));
    return r;
}

// ---------------------------------------------------------------------------
// Kernel PREP (fused):
//  blocks [0,2048): pack adj -> TRANSPOSED bitmask pb[word][grow] (uint32,
//    bit p of word w = adj[row][w*32+p]); k_attn mask loads are coalesced.
//  blocks [2048,2080): W fp32 -> wswz bf16 in MFMA B-frag order.
// ~11us floor (67MB adj read, HBM-bound) — left unchanged.
// ---------------------------------------------------------------------------
__global__ __launch_bounds__(256) void k_prep(const int* __restrict__ adj,
                                              const float* __restrict__ W,
                                              unsigned int* __restrict__ pb,
                                              unsigned short* __restrict__ wswz)
{
    int bx = blockIdx.x, t = threadIdx.x;
    if (bx < 2048) {
        int wave = t >> 6, lane = t & 63;
        int row = bx * 8 + wave * 2 + (lane >> 5);   // [0, 16384)
        int w   = lane & 31;
        const int4* ar = (const int4*)(adj + ((long)row << 10) + w * 32);
        unsigned int u = 0;
        #pragma unroll
        for (int k = 0; k < 8; k++) {
            int4 a = ar[k];
            u |= ((unsigned)a.x) << (4 * k);
            u |= ((unsigned)a.y) << (4 * k + 1);
            u |= ((unsigned)a.z) << (4 * k + 2);
            u |= ((unsigned)a.w) << (4 * k + 3);
        }
        pb[((long)w << 14) + row] = u;               // TRANSPOSED: [word][grow]
    } else {
        int slot = (bx - 2048) * 256 + t;
        int kstep = slot >> 10;
        int nt    = (slot >> 6) & 15;
        int lane  = slot & 63;
        int k0 = kstep * 32 + (lane >> 4) * 8;
        int n  = nt * 16 + (lane & 15);
        ushort4 o0, o1;
        o0.x = f2bf(W[(k0 + 0) * HD_ + n]);
        o0.y = f2bf(W[(k0 + 1) * HD_ + n]);
        o0.z = f2bf(W[(k0 + 2) * HD_ + n]);
        o0.w = f2bf(W[(k0 + 3) * HD_ + n]);
        o1.x = f2bf(W[(k0 + 4) * HD_ + n]);
        o1.y = f2bf(W[(k0 + 5) * HD_ + n]);
        o1.z = f2bf(W[(k0 + 6) * HD_ + n]);
        o1.w = f2bf(W[(k0 + 7) * HD_ + n]);
        *(ushort4*)&wswz[(long)slot * 8]     = o0;
        *(ushort4*)&wswz[(long)slot * 8 + 4] = o1;
    }
}

// ---------------------------------------------------------------------------
// Kernel A: h = x @ W via MFMA — 64-ROW BLOCKS for 4x B-frag reuse.
// Old form (16-row blocks) re-read the whole 128KB wswz per block from L2
// with a 1:1 load:MFMA ratio — the same MLP-starved in-loop-load pattern
// that bound k_attn for 8 rounds. Now: grid 256 x 256 thr (4 waves, one
// head each), 64 rows; per ks the 4 B-frags are loaded ONCE into regs and
// reused across 4 row-groups -> 16 MFMA per 4 loads, wswz L2 traffic
// 134MB -> 34MB. acc[4][4] f32x4 = 64 VGPR (statically indexed), ~110
// total; __launch_bounds__(256,4) caps at 128 (4 waves/SIMD). LDS 33.8KB.
// Emits hswz (B-frag order bf16) + per-row factors:
//   esr[(b,h,i)]  = exp2(-0.8*ss)   (E1 cancels in softmax -> dropped)
//   edst[(b,h,j)] = {exp2(sd), exp2(0.2*sd)}
// ---------------------------------------------------------------------------
__global__ __launch_bounds__(256, 4) void k_gemm_h(
    const float* __restrict__ x, const float* __restrict__ a,
    const unsigned short* __restrict__ wswz,
    unsigned short* __restrict__ hswz,
    float* __restrict__ esr, float2* __restrict__ edst)
{
    __shared__ unsigned short xls[64][264];
    int t = threadIdx.x;
    int blk = blockIdx.x;            // 256 blocks
    int row0 = blk * 64;
    int b  = blk >> 4;
    int n0 = row0 & 1023;

    {
        int sr0 = t >> 4, sc = (t & 15) * 16;
        #pragma unroll
        for (int rr = 0; rr < 4; rr++) {
            int sr = sr0 + rr * 16;
            const float* xp = x + (long)(row0 + sr) * INF_ + sc;
            float4 v0 = ((const float4*)xp)[0];
            float4 v1 = ((const float4*)xp)[1];
            float4 v2 = ((const float4*)xp)[2];
            float4 v3 = ((const float4*)xp)[3];
            ushort4 u0 = {f2bf(v0.x), f2bf(v0.y), f2bf(v0.z), f2bf(v0.w)};
            ushort4 u1 = {f2bf(v1.x), f2bf(v1.y), f2bf(v1.z), f2bf(v1.w)};
            ushort4 u2 = {f2bf(v2.x), f2bf(v2.y), f2bf(v2.z), f2bf(v2.w)};
            ushort4 u3 = {f2bf(v3.x), f2bf(v3.y), f2bf(v3.z), f2bf(v3.w)};
            *(ushort4*)&xls[sr][sc]      = u0;
            *(ushort4*)&xls[sr][sc + 4]  = u1;
            *(ushort4*)&xls[sr][sc + 8]  = u2;
            *(ushort4*)&xls[sr][sc + 12] = u3;
        }
    }
    __syncthreads();

    int wave = t >> 6, lane = t & 63, quad = lane >> 4, l15 = lane & 15;
    f32x4 acc[4][4];   // [rowgroup][nt] — all indices compile-time constant
    #pragma unroll
    for (int rg = 0; rg < 4; rg++)
        #pragma unroll
        for (int nt = 0; nt < 4; nt++) acc[rg][nt] = (f32x4){0.f, 0.f, 0.f, 0.f};

    #pragma unroll
    for (int ks = 0; ks < 8; ks++) {
        short8 bfr[4];
        #pragma unroll
        for (int nt = 0; nt < 4; nt++)
            bfr[nt] = *(const short8*)(wswz +
                ((long)((ks * 16 + wave * 4 + nt) * 64 + lane)) * 8);
        #pragma unroll
        for (int rg = 0; rg < 4; rg++) {
            short8 af = *(const short8*)&xls[rg * 16 + l15][ks * 32 + quad * 8];
            #pragma unroll
            for (int nt = 0; nt < 4; nt++)
                acc[rg][nt] = __builtin_amdgcn_mfma_f32_16x16x32_bf16(
                    af, bfr[nt], acc[rg][nt], 0, 0, 0);
        }
    }

    // hswz store (B-frag order for k_attn), per rowgroup
    int q0 = (quad & 1) * 4;
    #pragma unroll
    for (int rg = 0; rg < 4; rg++) {
        int row0g = row0 + rg * 16;
        int qd = ((row0g & 31) + quad * 4) >> 3;
        long bj32 = row0g >> 5;
        #pragma unroll
        for (int nt = 0; nt < 4; nt++) {
            int dg = wave * 4 + nt;
            long idx8 = (bj32 * 16 + dg) * 64 + qd * 16 + l15;
            ushort4 o = {f2bf(acc[rg][nt][0]), f2bf(acc[rg][nt][1]),
                         f2bf(acc[rg][nt][2]), f2bf(acc[rg][nt][3])};
            *(ushort4*)&hswz[idx8 * 8 + q0] = o;
        }
    }

    // fused scores -> row factor + exp pairs, pre-scaled by log2(e)
    float as_[4], ad_[4];
    #pragma unroll
    for (int nt = 0; nt < 4; nt++) {
        int d = nt * 16 + l15;
        as_[nt] = a[d * NH_ + wave];
        ad_[nt] = a[(64 + d) * NH_ + wave];
    }
    #pragma unroll
    for (int rg = 0; rg < 4; rg++) {
        #pragma unroll
        for (int r = 0; r < 4; r++) {
            float ps = acc[rg][0][r] * as_[0] + acc[rg][1][r] * as_[1]
                     + acc[rg][2][r] * as_[2] + acc[rg][3][r] * as_[3];
            float pd = acc[rg][0][r] * ad_[0] + acc[rg][1][r] * ad_[1]
                     + acc[rg][2][r] * ad_[2] + acc[rg][3][r] * ad_[3];
            #pragma unroll
            for (int m = 1; m < 16; m <<= 1) {
                ps += __shfl_xor(ps, m);
                pd += __shfl_xor(pd, m);
            }
            if (l15 == 0) {
                int row = n0 + rg * 16 + quad * 4 + r;
                float s1 = ps * L2E, s2 = pd * L2E;
                esr[((long)b * NH_ + wave) * N_ + row] = __builtin_exp2f(-0.8f * s1);
                edst[((long)b * NH_ + wave) * N_ + row] =
                    make_float2(__builtin_exp2f(s2), __builtin_exp2f(0.2f * s2));
            }
        }
    }
}

// ---------------------------------------------------------------------------
// Kernel C: masked softmax + MFMA aggregate — HIGH-REUSE BLOCKS (R9, best
// measured) + unroll 8. Occupancy ceiling is structural: 4096 independent
// 16-row wave-strips = 50% max without j-split, and R9 achieves it; the
// remaining lever is per-wave MLP depth. 1024-thr blocks run 1/CU so the
// effective VGPR cap is 128 — unroll 8 lets the scheduler keep ~8 jc
// bodies' loads in flight (~60 VGPR base + in-flight temps fits).
// grid = 256 blocks (16 b x 4 head x 4 rowgroups, XCD-swizzled: 2 b/XCD
// -> L2-resident) x 1024 thr = 16 waves = 16 strips of 16 rows. No jh
// split -> no cross-wave combine, no accb, no loop barriers. edst
// head-slice (8KB) staged once to LDS. pb transposed -> coalesced.
// __launch_bounds__(1024,4) = VGPR cap 128 (never min>=8: R2/R3 collapse).
// ---------------------------------------------------------------------------
__global__ __launch_bounds__(1024, 4) void k_attn(
    const unsigned int* __restrict__ pb, const unsigned short* __restrict__ hswz,
    const float* __restrict__ esr, const float2* __restrict__ edst,
    float* __restrict__ out)
{
    __shared__ float2 esb[1024];   // 8 KB: edst slice for (b, hh)
    __shared__ uint2 mtab[16];

    int t = threadIdx.x;
    int bid = blockIdx.x;
    int swz = (bid & 7) * 32 + (bid >> 3);   // bijective (256 % 8 == 0)
    int b  = swz >> 4;                        // 2 b per XCD -> L2-resident
    int hh = (swz >> 2) & 3;
    int rg = swz & 3;
    int row0 = rg * 256;

    int wave = t >> 6, lane = t & 63, quad = lane >> 4, l15 = lane & 15;

    esb[t] = edst[((long)(b * NH_ + hh)) * N_ + t];
    if (t < 16) {
        int k = t;
        unsigned int w0 = ((k & 1) ? 0xffffu : 0u) | ((k & 2) ? 0xffff0000u : 0u);
        unsigned int w1 = ((k & 4) ? 0xffffu : 0u) | ((k & 8) ? 0xffff0000u : 0u);
        mtab[k] = make_uint2(w0, w1);
    }
    __syncthreads();

    int irow = row0 + wave * 16 + l15;
    float r0 = esr[((long)(b * NH_ + hh)) * N_ + irow];
    // transposed pb: word jc at pb[jc*16384 + b*1024 + irow] (coalesced)
    const unsigned int* pbw = pb + ((long)b << 10) + irow;

    f32x4 acc[4], dn;
    #pragma unroll
    for (int i = 0; i < 4; i++) acc[i] = (f32x4){0.f, 0.f, 0.f, 0.f};
    dn = (f32x4){0.f, 0.f, 0.f, 0.f};
    short8 ones;
    #pragma unroll
    for (int i = 0; i < 8; i++) ones[i] = (short)0x3F80;   // bf16 1.0

    int shq = quad * 8;

    #pragma unroll 8
    for (int jc = 0; jc < 32; jc++) {
        unsigned int m0 = (pbw[((long)jc << 14)] >> shq) & 0xffu;
        const f32x4* ej = (const f32x4*)&esb[jc * 32 + quad * 8];

        union { unsigned int u[4]; short8 s; } p0;
        #pragma unroll
        for (int qp = 0; qp < 4; qp++) {
            f32x4 d = ej[qp];   // {D1_j, D2_j, D1_j', D2_j'} for j=2qp, 2qp+1
            p0.u[qp] = cvt_pk_bf16(fmaxf(d[0], r0 * d[1]), fmaxf(d[2], r0 * d[3]));
        }
        uint2 ma = mtab[m0 & 15u], mb = mtab[m0 >> 4];
        p0.u[0] &= ma.x; p0.u[1] &= ma.y; p0.u[2] &= mb.x; p0.u[3] &= mb.y;

        long s8 = ((long)(b * 32 + jc)) * 1024;
        #pragma unroll
        for (int idt = 0; idt < 4; idt++) {
            short8 bf = *(const short8*)(hswz + (s8 + (hh * 4 + idt) * 64 + lane) * 8);
            acc[idt] = __builtin_amdgcn_mfma_f32_16x16x32_bf16(p0.s, bf, acc[idt], 0, 0, 0);
        }
        dn = __builtin_amdgcn_mfma_f32_16x16x32_bf16(p0.s, ones, dn, 0, 0, 0);
    }

    // epilogue: per-wave normalize + store (no cross-wave combine at all)
    float inv[4];
    #pragma unroll
    for (int r = 0; r < 4; r++) inv[r] = 1.0f / dn[r];
    #pragma unroll
    for (int idt = 0; idt < 4; idt++) {
        int col = hh * 64 + idt * 16 + l15;
        #pragma unroll
        for (int r = 0; r < 4; r++) {
            long row_g = (long)b * N_ + row0 + wave * 16 + quad * 4 + r;
            out[row_g * HD_ + col] = acc[idt][r] * inv[r];
        }
    }
}

extern "C" void kernel_launch(void* const* d_in, const int* in_sizes, int n_in,
                              void* d_out, int out_size, void* d_ws, size_t ws_size,
                              hipStream_t stream) {
    const float* x   = (const float*)d_in[0];
    const int*   adj = (const int*)d_in[1];
    const float* W   = (const float*)d_in[2];
    const float* a   = (const float*)d_in[3];
    float* out = (float*)d_out;

    unsigned int* pb      = (unsigned int*)d_ws;                       // 2 MB
    unsigned short* hswz  = (unsigned short*)(pb + 524288);            // 8 MB
    unsigned short* wswz  = hswz + (long)B_ * N_ * HD_;                // 128 KB
    float* esr   = (float*)(wswz + INF_ * HD_);                        // 256 KB
    float2* edst = (float2*)(esr + (long)B_ * NH_ * N_);               // 512 KB

    k_prep<<<2080, 256, 0, stream>>>(adj, W, pb, wswz);
    k_gemm_h<<<256, 256, 0, stream>>>(x, a, wswz, hswz, esr, edst);
    k_attn<<<256, 1024, 0, stream>>>(pb, hswz, esr, edst, out);
}